// Round 9
// baseline (187.647 us; speedup 1.0000x reference)
//
#include <hip/hip_runtime.h>

typedef unsigned short u16;
typedef unsigned int u32;
typedef float f32x4 __attribute__((ext_vector_type(4)));
typedef __bf16 bf16x8 __attribute__((ext_vector_type(8)));
typedef u32 u32x4 __attribute__((ext_vector_type(4)));
typedef u32 u32x2 __attribute__((ext_vector_type(2)));
typedef short s16x4 __attribute__((ext_vector_type(4)));

#define LOG2E 1.44269504088896340736f

static __device__ __forceinline__ u16 f2bf(float f){ u32 u=__builtin_bit_cast(u32,f); u32 r=u+0x7fffu+((u>>16)&1u); return (u16)(r>>16); }
static __device__ __forceinline__ u32 pk2(float a,float b){ return (u32)f2bf(a)|((u32)f2bf(b)<<16); }
static __device__ __forceinline__ float fexp2(float x){
#if __has_builtin(__builtin_amdgcn_exp2f)
  return __builtin_amdgcn_exp2f(x);
#else
  float r; asm volatile("v_exp_f32 %0, %1" : "=v"(r) : "v"(x)); return r;
#endif
}
static __device__ __forceinline__ f32x4 mfma16(u32x4 a,u32x4 b,f32x4 c){
  return __builtin_amdgcn_mfma_f32_16x16x32_bf16(__builtin_bit_cast(bf16x8,a),__builtin_bit_cast(bf16x8,b),c,0,0,0);
}
#if __has_builtin(__builtin_amdgcn_mfma_f32_16x16x16bf16_1k)
static __device__ __forceinline__ f32x4 mfma1k(s16x4 a,s16x4 b,f32x4 c){
  return __builtin_amdgcn_mfma_f32_16x16x16bf16_1k(a,b,c,0,0,0);
}
#else
static __device__ __forceinline__ f32x4 mfma1k(s16x4 a,s16x4 b,f32x4 c){
  f32x4 d; asm("v_mfma_f32_16x16x16_bf16 %0, %1, %2, %3":"=v"(d):"v"(a),"v"(b),"v"(c)); return d;
}
#endif
static __device__ __forceinline__ u32x4 ld16(const u32* p){ return *(const u32x4*)p; }
static __device__ __forceinline__ s16x4 ld8(const u32* p){
  return __builtin_bit_cast(s16x4, *(const u32x2*)p);
}
static __device__ __forceinline__ void stlds(u32* d, uint4 v){
  *(uint2*)d = make_uint2(v.x,v.y); *(uint2*)(d+2) = make_uint2(v.z,v.w);
}
static __device__ __forceinline__ uint4 pack8(float4 a,float4 b){
  uint4 o; o.x=pk2(a.x,a.y); o.y=pk2(a.z,a.w); o.z=pk2(b.x,b.y); o.w=pk2(b.z,b.w); return o;
}

// ------------- group-norm stats: per-(group,slice) partial sums ---------------
__global__ __launch_bounds__(256) void k_stats(const float* __restrict__ x, const float* __restrict__ c,
                                               float* __restrict__ stats){
  const int g=blockIdx.x>>3;
  const float* src=(g<8?x:c)+(size_t)(g&7)*262144+(size_t)(blockIdx.x&7)*32768;
  const float4* p=(const float4*)src;
  const int t=threadIdx.x;
  float s1=0.f,s2=0.f;
  for(int i=0;i<32;i++){
    float4 v=p[t+i*256];
    s1+=v.x+v.y+v.z+v.w;
    s2+=v.x*v.x+v.y*v.y+v.z*v.z+v.w*v.w;
  }
  #pragma unroll
  for(int m=1;m<64;m<<=1){ s1+=__shfl_xor(s1,m,64); s2+=__shfl_xor(s2,m,64); }
  __shared__ float r1[4],r2[4];
  const int lane=t&63,w=t>>6;
  if(lane==0){ r1[w]=s1; r2[w]=s2; }
  __syncthreads();
  if(t==0){
    stats[blockIdx.x*2  ]=r1[0]+r1[1]+r1[2]+r1[3];
    stats[blockIdx.x*2+1]=r2[0]+r2[1]+r2[2]+r2[3];
  }
}

// -------- k_norm: (a) normalize+transpose x/ctx -> bf16 [s][c]; (b) weights->bf16
// blocks [0,256): transpose tiles 64c x 256s (128 per operand).
// blocks [256,288): convert pw|qw|kvw fp32 -> Wall bf16 ([pwb][qwb][kvwb]).
__global__ __launch_bounds__(256) void k_norm(const float* __restrict__ x,const float* __restrict__ ctx,
    const float* __restrict__ qw,const float* __restrict__ kvw,const float* __restrict__ pw,
    const float* __restrict__ nw,const float* __restrict__ nb,
    const float* __restrict__ ncw,const float* __restrict__ ncb,
    const float* __restrict__ stats,
    u16* __restrict__ xnT,u16* __restrict__ cnT,u16* __restrict__ Wall){
  const int bid=blockIdx.x, t=threadIdx.x;
  if(bid>=256){
    const int wb=bid-256;
    const float* src = wb<8 ? pw+(size_t)wb*32768 : (wb<16 ? qw+(size_t)(wb-8)*32768 : kvw+(size_t)(wb-16)*32768);
    u16* dst = Wall + (size_t)wb*32768;
    #pragma unroll
    for(int it=0;it<16;it++){
      int off = it*2048 + t*8;
      float4 a=*(const float4*)(src+off), b=*(const float4*)(src+off+4);
      *(uint4*)(dst+off) = pack8(a,b);
    }
    return;
  }
  const int op=bid>>7, r=bid&127;
  const int c0=(r>>4)*64, s0=(r&15)*256;
  const float* src = op? ctx : x;
  u16* dst = op? cnT : xnT;
  const float* anw = op? ncw : nw;
  const float* anb = op? ncb : nb;
  __shared__ float al[64], bt[64];
  __shared__ u32 T[256*37];
  if(t<64){
    int c=c0+t, g=(op?8:0)+(c>>6);
    float s1=0.f,s2=0.f;
    #pragma unroll
    for(int s=0;s<8;s++){ s1+=stats[(g*8+s)*2]; s2+=stats[(g*8+s)*2+1]; }
    float mean=s1*(1.f/262144.f);
    float var =s2*(1.f/262144.f)-mean*mean;
    float a=anw[c]*rsqrtf(var+1e-5f);
    al[t]=a; bt[t]=anb[c]-mean*a;
  }
  __syncthreads();
  const int pr=t>>3, sj=(t&7)*8;
  const float a0=al[2*pr], b0=bt[2*pr], a1=al[2*pr+1], b1=bt[2*pr+1];
  #pragma unroll
  for(int it=0;it<4;it++){
    int ls=it*64+sj;
    const float* p0=src+(size_t)(c0+2*pr)*4096+s0+ls;
    const float* p1=src+(size_t)(c0+2*pr+1)*4096+s0+ls;
    float4 va=*(const float4*)p0, vb=*(const float4*)(p0+4);
    float4 vc=*(const float4*)p1, vd=*(const float4*)(p1+4);
    float f0[8]={va.x,va.y,va.z,va.w,vb.x,vb.y,vb.z,vb.w};
    float f1[8]={vc.x,vc.y,vc.z,vc.w,vd.x,vd.y,vd.z,vd.w};
    #pragma unroll
    for(int j=0;j<8;j++)
      T[(ls+j)*37+pr]=pk2(a0*f0[j]+b0, a1*f1[j]+b1);
  }
  __syncthreads();
  #pragma unroll
  for(int ps=0;ps<8;ps++){
    int row = ps*32 + (t>>3);
    const u32* rp=&T[row*37+(t&7)*4];
    u32 v0=rp[0],v1=rp[1],v2=rp[2],v3=rp[3];
    *(uint4*)(dst + (size_t)(s0+row)*512 + c0 + (t&7)*8) = make_uint4(v0,v1,v2,v3);
  }
}

// --------- unified bf16 BT GEMM: C[m][n]=sum_k A[m][k]B[n][k], K=512 ----------
// BM=BN=128, BK=32, 256 thr (2x2 waves, wave tile 64x64), dbuf LDS stride 20.
// EPI 0: head-layout store (m=s, n=co), bias[n], *scale; M=4096,N=512 (Q/K)
// EPI 1: bf16 out[m*4096+n]+bias[m]; M=512,N=4096 (V)
// EPI 2: fp32 out[m*4096+n]+bias[m]+resid; M=512,N=4096 (proj)
// BG 1: B gathered from head layout [k/64][4096][64] (proj reading Oh)
// ZS 1: bid>>7 selects operand set (Q vs K in one dispatch)
template<int EPI,int BG,int ZS>
__global__ __launch_bounds__(256,2) void k_gemm(const u16* __restrict__ A0,const u16* __restrict__ A1,
    const u16* __restrict__ B0,const u16* __restrict__ B1,
    const float* __restrict__ bias0,const float* __restrict__ bias1,
    const float* __restrict__ residf,void* __restrict__ out0,void* __restrict__ out1,
    float scale0,float scale1){
  __shared__ __align__(16) u32 As[2][128*20];
  __shared__ __align__(16) u32 Bs[2][128*20];
  const int t=threadIdx.x, lane=t&63, w=t>>6;
  const int wm=w&1, wn=w>>1, quad=lane>>4, l15=lane&15;
  const int bid=blockIdx.x;
  const int z = ZS ? (bid>>7) : 0;
  const int r = ZS ? (bid&127) : bid;
  const u16* A = z? A1:A0;
  const u16* B = z? B1:B0;
  const float* bias = z? bias1:bias0;
  void* outv = z? out1:out0;
  const float scale = z? scale1:scale0;
  int m0,n0;
  if(EPI==0){ m0=(r>>2)*128; n0=(r&3)*128; }
  else      { m0=(r>>5)*128; n0=(r&31)*128; }
  const int arow=t>>1, ak=(t&1)*16;
  uint4 a0,a1,b0,b1;
  auto loadAB=[&](int kk){
    const u16* ap=A+(size_t)(m0+arow)*512+kk+ak;
    a0=*(const uint4*)ap; a1=*(const uint4*)(ap+8);
    const u16* bp;
    if(BG) bp = B + ((size_t)((kk>>6)*4096 + n0+arow))*64 + (kk&63) + ak;
    else   bp = B + (size_t)(n0+arow)*512 + kk + ak;
    b0=*(const uint4*)bp; b1=*(const uint4*)(bp+8);
  };
  auto writeAB=[&](int bsel){
    u32* aw=&As[bsel][arow*20+(ak>>1)];
    stlds(aw,a0); stlds(aw+4,a1);
    u32* bw=&Bs[bsel][arow*20+(ak>>1)];
    stlds(bw,b0); stlds(bw+4,b1);
  };
  f32x4 acc[4][4];
  #pragma unroll
  for(int i=0;i<4;i++)
    #pragma unroll
    for(int j=0;j<4;j++){ acc[i][j].x=0.f; acc[i][j].y=0.f; acc[i][j].z=0.f; acc[i][j].w=0.f; }
  auto compute=[&](int bsel){
    const u32* Ab=&As[bsel][(wm*64+l15)*20+quad*4];
    const u32* Bb=&Bs[bsel][(wn*64+l15)*20+quad*4];
    u32x4 af[4], bf[4];
    #pragma unroll
    for(int mt=0;mt<4;mt++) af[mt]=ld16(Ab+mt*320);
    #pragma unroll
    for(int nt=0;nt<4;nt++) bf[nt]=ld16(Bb+nt*320);
    #pragma unroll
    for(int mt=0;mt<4;mt++)
      #pragma unroll
      for(int nt=0;nt<4;nt++) acc[mt][nt]=mfma16(af[mt],bf[nt],acc[mt][nt]);
  };
  loadAB(0); writeAB(0);
  __syncthreads();
  for(int kk=0;kk<512;kk+=64){
    loadAB(kk+32);
    compute(0);
    writeAB(1);
    __syncthreads();
    const bool n2=(kk+64)<512;
    if(n2) loadAB(kk+64);
    compute(1);
    if(n2){ writeAB(0); __syncthreads(); }
  }
  #pragma unroll
  for(int mt=0;mt<4;mt++)
    #pragma unroll
    for(int nt=0;nt<4;nt++){
      const int n = n0 + wn*64 + nt*16 + l15;
      if(EPI==0){
        u16* out=(u16*)outv;
        const float bn=bias[n];
        const size_t base=((size_t)((n>>6)*4096))*64+(size_t)(n&63);
        #pragma unroll
        for(int r4=0;r4<4;r4++){
          int m=m0+wm*64+mt*16+quad*4+r4;
          out[base+(size_t)m*64]=f2bf((acc[mt][nt][r4]+bn)*scale);
        }
      }else if(EPI==1){
        u16* out=(u16*)outv;
        #pragma unroll
        for(int r4=0;r4<4;r4++){
          int m=m0+wm*64+mt*16+quad*4+r4;
          out[(size_t)m*4096+n]=f2bf(acc[mt][nt][r4]+bias[m]);
        }
      }else{
        float* out=(float*)outv;
        #pragma unroll
        for(int r4=0;r4<4;r4++){
          int m=m0+wm*64+mt*16+quad*4+r4;
          out[(size_t)m*4096+n]=acc[mt][nt][r4]+bias[m]+residf[(size_t)m*4096+n];
        }
      }
    }
}

// -------- flash attention: 128q blocks, 2 q-frags/wave, split-K halves --------
// S^T = K·Q^T (16x16x32, A=K from LDS b128, B=Q regs); exp2'd scores feed
// P·V (16x16x16) straight from registers. K/V frags serve both q-tiles ->
// half the LDS bandwidth per query. No-max exp2 softmax (bounded scores).
__global__ __launch_bounds__(512) void k_attn(const u16* __restrict__ Qh,const u16* __restrict__ Kh,
                                              const u16* __restrict__ Vp,u16* __restrict__ Oh){
  __shared__ __align__(16) u32 KS[2][2][64*36];   // [half][buf][key][c], stride 36
  __shared__ __align__(16) u32 VS[2][2][64*36];   // [half][buf][c][key]
  const int t=threadIdx.x, lane=t&63, w=t>>6, quad=lane>>4, l15=lane&15;
  const int half=w>>2, wq=w&3;
  const int h=blockIdx.y, q0=blockIdx.x*128;
  const int tt=t&255, srow=tt>>2, sc=(tt&3)*16;
  const u16* Kg = Kh + ((size_t)(h*4096 + half*2048 + srow))*64 + sc;
  const u16* Vg = Vp + (size_t)(h*64+srow)*4096 + half*2048 + sc;
  u32x4 qf[2][2];
  #pragma unroll
  for(int qt=0;qt<2;qt++){
    const u32* Qg=(const u32*)(Qh + ((size_t)(h*4096+q0+qt*64+wq*16+l15))*64);
    qf[qt][0]=ld16(Qg+quad*4);
    qf[qt][1]=ld16(Qg+16+quad*4);
  }
  uint4 pk0,pk1,pv0,pv1;
  auto loadKV=[&](int t0l){
    const u16* kp=Kg+(size_t)t0l*64;
    pk0=*(const uint4*)kp; pk1=*(const uint4*)(kp+8);
    const u16* vp=Vg+t0l;
    pv0=*(const uint4*)vp; pv1=*(const uint4*)(vp+8);
  };
  auto writeKV=[&](u32* Kb,u32* Vb){
    u32* kw=Kb+srow*36+(sc>>1);
    stlds(kw,pk0); stlds(kw+4,pk1);
    u32* vw=Vb+srow*36+(sc>>1);
    stlds(vw,pv0); stlds(vw+4,pv1);
  };
  float lrun[2]={0.f,0.f};
  f32x4 oacc[2][4];
  #pragma unroll
  for(int qt=0;qt<2;qt++)
    #pragma unroll
    for(int cn=0;cn<4;cn++){ oacc[qt][cn].x=0.f; oacc[qt][cn].y=0.f; oacc[qt][cn].z=0.f; oacc[qt][cn].w=0.f; }

  auto tilestep=[&](const u32* Kb,const u32* Vb){
    f32x4 sv[2][4];
    #pragma unroll
    for(int nt=0;nt<4;nt++){
      const u32* kb=Kb+(nt*16+l15)*36+quad*4;
      u32x4 k0=ld16(kb), k1=ld16(kb+16);
      #pragma unroll
      for(int qt=0;qt<2;qt++){
        f32x4 a; a.x=0.f; a.y=0.f; a.z=0.f; a.w=0.f;
        a=mfma16(k0,qf[qt][0],a);
        sv[qt][nt]=mfma16(k1,qf[qt][1],a);
      }
    }
    s16x4 pfr[2][4];
    #pragma unroll
    for(int qt=0;qt<2;qt++)
      #pragma unroll
      for(int nt=0;nt<4;nt++){
        float p0=fexp2(sv[qt][nt].x),p1=fexp2(sv[qt][nt].y),p2=fexp2(sv[qt][nt].z),p3=fexp2(sv[qt][nt].w);
        lrun[qt]+=(p0+p1)+(p2+p3);
        u32x2 pp;
        pp.x=(__builtin_bit_cast(u32,p0)>>16)|(__builtin_bit_cast(u32,p1)&0xffff0000u);
        pp.y=(__builtin_bit_cast(u32,p2)>>16)|(__builtin_bit_cast(u32,p3)&0xffff0000u);
        pfr[qt][nt]=__builtin_bit_cast(s16x4,pp);
      }
    #pragma unroll
    for(int cn=0;cn<4;cn++){
      const u32* vb=Vb+(cn*16+l15)*36+quad*2;
      f32x4 a0=oacc[0][cn], a1=oacc[1][cn];
      #pragma unroll
      for(int nt=0;nt<4;nt++){
        s16x4 vf=ld8(vb+nt*8);
        a0=mfma1k(pfr[0][nt],vf,a0);
        a1=mfma1k(pfr[1][nt],vf,a1);
      }
      oacc[0][cn]=a0; oacc[1][cn]=a1;
    }
  };

  loadKV(0); writeKV(KS[half][0],VS[half][0]);
  __syncthreads();
  for(int t0=0;t0<2048;t0+=128){
    loadKV(t0+64);
    tilestep(KS[half][0],VS[half][0]);
    writeKV(KS[half][1],VS[half][1]);
    __syncthreads();
    const bool more=(t0+128)<2048;
    if(more) loadKV(t0+128);
    tilestep(KS[half][1],VS[half][1]);
    if(more){ writeKV(KS[half][0],VS[half][0]); __syncthreads(); }
  }
  // merge halves through LDS (reuse KS; all K reads done)
  __syncthreads();
  float* cb=(float*)KS;
  const int cbi=(wq*64+lane)*34;
  if(half==1){
    #pragma unroll
    for(int qt=0;qt<2;qt++)
      #pragma unroll
      for(int cn=0;cn<4;cn++)
        #pragma unroll
        for(int r4=0;r4<4;r4++) cb[cbi+qt*16+cn*4+r4]=oacc[qt][cn][r4];
    cb[cbi+32]=lrun[0]; cb[cbi+33]=lrun[1];
  }
  __syncthreads();
  if(half==0){
    #pragma unroll
    for(int qt=0;qt<2;qt++){
      #pragma unroll
      for(int cn=0;cn<4;cn++)
        #pragma unroll
        for(int r4=0;r4<4;r4++) oacc[qt][cn][r4]+=cb[cbi+qt*16+cn*4+r4];
      float l=lrun[qt]+cb[cbi+32+qt];
      l+=__shfl_xor(l,16,64);
      l+=__shfl_xor(l,32,64);
      #pragma unroll
      for(int r4=0;r4<4;r4++){
        float inv=1.f/__shfl(l,quad*4+r4,64);
        #pragma unroll
        for(int cn=0;cn<4;cn++)
          Oh[((size_t)(h*4096+q0+qt*64+wq*16+quad*4+r4))*64 + cn*16 + l15]=f2bf(oacc[qt][cn][r4]*inv);
      }
    }
  }
}

// ------------------------------- launcher -------------------------------------
extern "C" void kernel_launch(void* const* d_in, const int* in_sizes, int n_in,
                              void* d_out, int out_size, void* d_ws, size_t ws_size,
                              hipStream_t stream){
  (void)in_sizes; (void)n_in; (void)out_size; (void)ws_size;
  const float* x  =(const float*)d_in[0];
  const float* ctx=(const float*)d_in[1];
  const float* nw =(const float*)d_in[2];
  const float* nb =(const float*)d_in[3];
  const float* ncw=(const float*)d_in[4];
  const float* ncb=(const float*)d_in[5];
  const float* qw =(const float*)d_in[6];
  const float* qb =(const float*)d_in[7];
  const float* kvw=(const float*)d_in[8];
  const float* kvb=(const float*)d_in[9];
  const float* pw =(const float*)d_in[10];
  const float* pb =(const float*)d_in[11];
  float* out=(float*)d_out;
  char* ws=(char*)d_ws;
  float* stats=(float*)ws;                    // 1 KB
  u16* Wall=(u16*)(ws+1024);                  // [pwb 256K][qwb 256K][kvwb 512K] elems -> 2 MB
  u16* pwb  = Wall;
  u16* qwb  = Wall+262144;
  u16* kvw1b= Wall+524288;
  u16* kvw2b= Wall+786432;
  u16* cnT=(u16*)(ws+2098176);                // [4096][512] bf16, 4 MB
  u16* xnT=(u16*)(ws+6292480);                // 4 MB
  u16* Qh =(u16*)(ws+10486784);               // [8][4096][64]
  u16* Kh =(u16*)(ws+14681088);               // ends 18875392 (~18.0 MB)
  u16* Vp =(u16*)(ws+6292480);                // overlays xnT (dead after Q/K GEMM)
  u16* Oh =(u16*)(ws+2098176);                // overlays cnT (dead after V GEMM)

  k_stats<<<dim3(128),dim3(256),0,stream>>>(x,ctx,stats);
  k_norm<<<dim3(288),dim3(256),0,stream>>>(x,ctx,qw,kvw,pw,nw,nb,ncw,ncb,stats,xnT,cnT,Wall);
  // Q (z=0) and K (z=1) in one dispatch
  k_gemm<0,0,1><<<dim3(256),dim3(256),0,stream>>>(xnT,cnT,qwb,kvw1b,qb,kvb,nullptr,Qh,Kh,0.125f*LOG2E,1.f);
  // V[co][s] = Wv · cn
  k_gemm<1,0,0><<<dim3(128),dim3(256),0,stream>>>(kvw2b,nullptr,cnT,nullptr,kvb+512,nullptr,nullptr,Vp,nullptr,1.f,1.f);
  k_attn<<<dim3(32,8),dim3(512),0,stream>>>(Qh,Kh,Vp,Oh);
  // proj + residual (fp32 out)
  k_gemm<2,1,0><<<dim3(128),dim3(256),0,stream>>>(pwb,nullptr,Oh,nullptr,pb,nullptr,x,out,nullptr,1.f,1.f);
}

// Round 10
// 181.238 us; speedup vs baseline: 1.0354x; 1.0354x over previous
//
#include <hip/hip_runtime.h>

typedef unsigned short u16;
typedef unsigned int u32;
typedef float f32x4 __attribute__((ext_vector_type(4)));
typedef __bf16 bf16x8 __attribute__((ext_vector_type(8)));
typedef u32 u32x4 __attribute__((ext_vector_type(4)));
typedef u32 u32x2 __attribute__((ext_vector_type(2)));
typedef short s16x4 __attribute__((ext_vector_type(4)));

#define LOG2E 1.44269504088896340736f

static __device__ __forceinline__ u16 f2bf(float f){ u32 u=__builtin_bit_cast(u32,f); u32 r=u+0x7fffu+((u>>16)&1u); return (u16)(r>>16); }
static __device__ __forceinline__ u32 pk2(float a,float b){ return (u32)f2bf(a)|((u32)f2bf(b)<<16); }
static __device__ __forceinline__ float fexp2(float x){
#if __has_builtin(__builtin_amdgcn_exp2f)
  return __builtin_amdgcn_exp2f(x);
#else
  float r; asm volatile("v_exp_f32 %0, %1" : "=v"(r) : "v"(x)); return r;
#endif
}
static __device__ __forceinline__ f32x4 mfma16(u32x4 a,u32x4 b,f32x4 c){
  return __builtin_amdgcn_mfma_f32_16x16x32_bf16(__builtin_bit_cast(bf16x8,a),__builtin_bit_cast(bf16x8,b),c,0,0,0);
}
#if __has_builtin(__builtin_amdgcn_mfma_f32_16x16x16bf16_1k)
static __device__ __forceinline__ f32x4 mfma1k(s16x4 a,s16x4 b,f32x4 c){
  return __builtin_amdgcn_mfma_f32_16x16x16bf16_1k(a,b,c,0,0,0);
}
#else
static __device__ __forceinline__ f32x4 mfma1k(s16x4 a,s16x4 b,f32x4 c){
  f32x4 d; asm("v_mfma_f32_16x16x16_bf16 %0, %1, %2, %3":"=v"(d):"v"(a),"v"(b),"v"(c)); return d;
}
#endif
static __device__ __forceinline__ u32x4 ldfrag(const u32* p){
  uint2 a=*(const uint2*)p; uint2 b=*(const uint2*)(p+2);
  u32x4 r; r.x=a.x; r.y=a.y; r.z=b.x; r.w=b.y; return r;
}
static __device__ __forceinline__ u32x4 ld16(const u32* p){ return *(const u32x4*)p; }
static __device__ __forceinline__ s16x4 ld8(const u32* p){
  return __builtin_bit_cast(s16x4, *(const u32x2*)p);
}
static __device__ __forceinline__ void stlds(u32* d, uint4 v){
  *(uint2*)d = make_uint2(v.x,v.y); *(uint2*)(d+2) = make_uint2(v.z,v.w);
}
static __device__ __forceinline__ uint4 pack8(float4 a,float4 b){
  uint4 o; o.x=pk2(a.x,a.y); o.y=pk2(a.z,a.w); o.z=pk2(b.x,b.y); o.w=pk2(b.z,b.w); return o;
}

// ------------- group-norm stats: per-(group,slice) partial sums ---------------
__global__ __launch_bounds__(256) void k_stats(const float* __restrict__ x, const float* __restrict__ c,
                                               float* __restrict__ stats){
  const int g=blockIdx.x>>3;
  const float* src=(g<8?x:c)+(size_t)(g&7)*262144+(size_t)(blockIdx.x&7)*32768;
  const float4* p=(const float4*)src;
  const int t=threadIdx.x;
  float s1=0.f,s2=0.f;
  for(int i=0;i<32;i++){
    float4 v=p[t+i*256];
    s1+=v.x+v.y+v.z+v.w;
    s2+=v.x*v.x+v.y*v.y+v.z*v.z+v.w*v.w;
  }
  #pragma unroll
  for(int m=1;m<64;m<<=1){ s1+=__shfl_xor(s1,m,64); s2+=__shfl_xor(s2,m,64); }
  __shared__ float r1[4],r2[4];
  const int lane=t&63,w=t>>6;
  if(lane==0){ r1[w]=s1; r2[w]=s2; }
  __syncthreads();
  if(t==0){
    stats[blockIdx.x*2  ]=r1[0]+r1[1]+r1[2]+r1[3];
    stats[blockIdx.x*2+1]=r2[0]+r2[1]+r2[2]+r2[3];
  }
}

// -------- k_norm: (a) normalize+transpose x/ctx -> bf16 [s][c]; (b) weights->bf16
__global__ __launch_bounds__(256) void k_norm(const float* __restrict__ x,const float* __restrict__ ctx,
    const float* __restrict__ qw,const float* __restrict__ kvw,const float* __restrict__ pw,
    const float* __restrict__ nw,const float* __restrict__ nb,
    const float* __restrict__ ncw,const float* __restrict__ ncb,
    const float* __restrict__ stats,
    u16* __restrict__ xnT,u16* __restrict__ cnT,u16* __restrict__ Wall){
  const int bid=blockIdx.x, t=threadIdx.x;
  if(bid>=256){
    const int wb=bid-256;
    const float* src = wb<8 ? pw+(size_t)wb*32768 : (wb<16 ? qw+(size_t)(wb-8)*32768 : kvw+(size_t)(wb-16)*32768);
    u16* dst = Wall + (size_t)wb*32768;
    #pragma unroll
    for(int it=0;it<16;it++){
      int off = it*2048 + t*8;
      float4 a=*(const float4*)(src+off), b=*(const float4*)(src+off+4);
      *(uint4*)(dst+off) = pack8(a,b);
    }
    return;
  }
  const int op=bid>>7, r=bid&127;
  const int c0=(r>>4)*64, s0=(r&15)*256;
  const float* src = op? ctx : x;
  u16* dst = op? cnT : xnT;
  const float* anw = op? ncw : nw;
  const float* anb = op? ncb : nb;
  __shared__ float al[64], bt[64];
  __shared__ u32 T[256*37];
  if(t<64){
    int c=c0+t, g=(op?8:0)+(c>>6);
    float s1=0.f,s2=0.f;
    #pragma unroll
    for(int s=0;s<8;s++){ s1+=stats[(g*8+s)*2]; s2+=stats[(g*8+s)*2+1]; }
    float mean=s1*(1.f/262144.f);
    float var =s2*(1.f/262144.f)-mean*mean;
    float a=anw[c]*rsqrtf(var+1e-5f);
    al[t]=a; bt[t]=anb[c]-mean*a;
  }
  __syncthreads();
  const int pr=t>>3, sj=(t&7)*8;
  const float a0=al[2*pr], b0=bt[2*pr], a1=al[2*pr+1], b1=bt[2*pr+1];
  #pragma unroll
  for(int it=0;it<4;it++){
    int ls=it*64+sj;
    const float* p0=src+(size_t)(c0+2*pr)*4096+s0+ls;
    const float* p1=src+(size_t)(c0+2*pr+1)*4096+s0+ls;
    float4 va=*(const float4*)p0, vb=*(const float4*)(p0+4);
    float4 vc=*(const float4*)p1, vd=*(const float4*)(p1+4);
    float f0[8]={va.x,va.y,va.z,va.w,vb.x,vb.y,vb.z,vb.w};
    float f1[8]={vc.x,vc.y,vc.z,vc.w,vd.x,vd.y,vd.z,vd.w};
    #pragma unroll
    for(int j=0;j<8;j++)
      T[(ls+j)*37+pr]=pk2(a0*f0[j]+b0, a1*f1[j]+b1);
  }
  __syncthreads();
  #pragma unroll
  for(int ps=0;ps<8;ps++){
    int row = ps*32 + (t>>3);
    const u32* rp=&T[row*37+(t&7)*4];
    u32 v0=rp[0],v1=rp[1],v2=rp[2],v3=rp[3];
    *(uint4*)(dst + (size_t)(s0+row)*512 + c0 + (t&7)*8) = make_uint4(v0,v1,v2,v3);
  }
}

// --------- unified bf16 BT GEMM: C[m][n]=sum_k A[m][k]B[n][k], K=512 ----------
// BM=64, BN=128, BK=32, 256 thr (wave tile 32x64), stride-18 LDS (0 conflicts),
// dbuf unrolled x2, single barrier/phase. All operands bf16, pure-copy staging.
// EPI 0: head-layout store (m=s, n=co), bias[n], *scale (Q/K; ZS selects set)
// EPI 1: bf16 out[m*4096+n]+bias[m]  (V)
// EPI 2: fp32 out[m*4096+n]+bias[m]+resid (proj; BG=1 gathers B from head layout)
template<int EPI,int BG,int ZS>
__global__ __launch_bounds__(256) void k_gemm(const u16* __restrict__ A0,const u16* __restrict__ A1,
    const u16* __restrict__ B0,const u16* __restrict__ B1,
    const float* __restrict__ bias0,const float* __restrict__ bias1,
    const float* __restrict__ residf,void* __restrict__ out0,void* __restrict__ out1,
    float scale0,float scale1){
  __shared__ __align__(16) u32 As[2][64*18];
  __shared__ __align__(16) u32 Bs[2][128*18];
  const int t=threadIdx.x, lane=t&63, w=t>>6;
  const int wm=w&1, wn=w>>1, quad=lane>>4, l15=lane&15;
  const int bid=blockIdx.x;
  const int z = ZS ? (bid>>8) : 0;
  const int r = ZS ? (bid&255) : bid;
  const u16* A = z? A1:A0;
  const u16* B = z? B1:B0;
  const float* bias = z? bias1:bias0;
  void* outv = z? out1:out0;
  const float scale = z? scale1:scale0;
  int m0,n0;
  if(EPI==0){ m0=(r>>2)*64; n0=(r&3)*128; }
  else      { m0=(r>>5)*64; n0=(r&31)*128; }
  const int arow=t>>2, ak=(t&3)*8;
  uint4 a0,b0,b1;
  auto loadAB=[&](int kk){
    a0=*(const uint4*)(A+(size_t)(m0+arow)*512+kk+ak);
    const u16 *bp0,*bp1;
    if(BG){
      bp0 = B + ((size_t)((kk>>6)*4096 + n0+arow))*64 + (kk&63) + ak;
      bp1 = B + ((size_t)((kk>>6)*4096 + n0+64+arow))*64 + (kk&63) + ak;
    }else{
      bp0 = B + (size_t)(n0+arow)*512 + kk + ak;
      bp1 = B + (size_t)(n0+64+arow)*512 + kk + ak;
    }
    b0=*(const uint4*)bp0; b1=*(const uint4*)bp1;
  };
  auto writeAB=[&](int bsel){
    stlds(&As[bsel][arow*18+(ak>>1)],a0);
    stlds(&Bs[bsel][arow*18+(ak>>1)],b0);
    stlds(&Bs[bsel][(64+arow)*18+(ak>>1)],b1);
  };
  f32x4 acc[2][4];
  #pragma unroll
  for(int i=0;i<2;i++)
    #pragma unroll
    for(int j=0;j<4;j++){ acc[i][j].x=0.f; acc[i][j].y=0.f; acc[i][j].z=0.f; acc[i][j].w=0.f; }
  auto compute=[&](int bsel){
    const u32* Ab=&As[bsel][(wm*32+l15)*18+quad*4];
    const u32* Bb=&Bs[bsel][(wn*64+l15)*18+quad*4];
    u32x4 af[2], bf[4];
    #pragma unroll
    for(int mt=0;mt<2;mt++) af[mt]=ldfrag(Ab+mt*288);
    #pragma unroll
    for(int nt=0;nt<4;nt++) bf[nt]=ldfrag(Bb+nt*288);
    #pragma unroll
    for(int mt=0;mt<2;mt++)
      #pragma unroll
      for(int nt=0;nt<4;nt++) acc[mt][nt]=mfma16(af[mt],bf[nt],acc[mt][nt]);
  };
  loadAB(0); writeAB(0);
  __syncthreads();
  for(int kk=0;kk<512;kk+=64){
    loadAB(kk+32);
    compute(0);
    writeAB(1);
    __syncthreads();
    const bool n2=(kk+64)<512;
    if(n2) loadAB(kk+64);
    compute(1);
    if(n2){ writeAB(0); __syncthreads(); }
  }
  #pragma unroll
  for(int mt=0;mt<2;mt++)
    #pragma unroll
    for(int nt=0;nt<4;nt++){
      const int n = n0 + wn*64 + nt*16 + l15;
      if(EPI==0){
        u16* out=(u16*)outv;
        const float bn=bias[n];
        const size_t base=((size_t)((n>>6)*4096))*64+(size_t)(n&63);
        #pragma unroll
        for(int r4=0;r4<4;r4++){
          int m=m0+wm*32+mt*16+quad*4+r4;
          out[base+(size_t)m*64]=f2bf((acc[mt][nt][r4]+bn)*scale);
        }
      }else if(EPI==1){
        u16* out=(u16*)outv;
        #pragma unroll
        for(int r4=0;r4<4;r4++){
          int m=m0+wm*32+mt*16+quad*4+r4;
          out[(size_t)m*4096+n]=f2bf(acc[mt][nt][r4]+bias[m]);
        }
      }else{
        float* out=(float*)outv;
        #pragma unroll
        for(int r4=0;r4<4;r4++){
          int m=m0+wm*32+mt*16+quad*4+r4;
          out[(size_t)m*4096+n]=acc[mt][nt][r4]+bias[m]+residf[(size_t)m*4096+n];
        }
      }
    }
}

// -------- flash attention: 128q blocks, 2 q-frags/wave, split-K halves --------
// Stride-34 LDS rows (bank base 2r: 16 distinct rows -> 0 conflicts, R4-R8
// verified). S^T = K·Q^T (16x16x32, A=K b64-pairs, B=Q regs); exp2'd scores
// feed P·V (16x16x16) from registers. No-max exp2 softmax (bounded scores).
__global__ __launch_bounds__(512) void k_attn(const u16* __restrict__ Qh,const u16* __restrict__ Kh,
                                              const u16* __restrict__ Vp,u16* __restrict__ Oh){
  __shared__ __align__(16) u32 KS[2][2][64*34];   // [half][buf][key][c]
  __shared__ __align__(16) u32 VS[2][2][64*34];   // [half][buf][c][key]
  const int t=threadIdx.x, lane=t&63, w=t>>6, quad=lane>>4, l15=lane&15;
  const int half=w>>2, wq=w&3;
  const int h=blockIdx.y, q0=blockIdx.x*128;
  const int tt=t&255, srow=tt>>2, sc=(tt&3)*16;
  const u16* Kg = Kh + ((size_t)(h*4096 + half*2048 + srow))*64 + sc;
  const u16* Vg = Vp + (size_t)(h*64+srow)*4096 + half*2048 + sc;
  u32x4 qf[2][2];
  #pragma unroll
  for(int qt=0;qt<2;qt++){
    const u32* Qg=(const u32*)(Qh + ((size_t)(h*4096+q0+qt*64+wq*16+l15))*64);
    qf[qt][0]=ld16(Qg+quad*4);
    qf[qt][1]=ld16(Qg+16+quad*4);
  }
  uint4 pk0,pk1,pv0,pv1;
  auto loadKV=[&](int t0l){
    const u16* kp=Kg+(size_t)t0l*64;
    pk0=*(const uint4*)kp; pk1=*(const uint4*)(kp+8);
    const u16* vp=Vg+t0l;
    pv0=*(const uint4*)vp; pv1=*(const uint4*)(vp+8);
  };
  auto writeKV=[&](u32* Kb,u32* Vb){
    u32* kw=Kb+srow*34+(sc>>1);
    stlds(kw,pk0); stlds(kw+4,pk1);
    u32* vw=Vb+srow*34+(sc>>1);
    stlds(vw,pv0); stlds(vw+4,pv1);
  };
  float lrun[2]={0.f,0.f};
  f32x4 oacc[2][4];
  #pragma unroll
  for(int qt=0;qt<2;qt++)
    #pragma unroll
    for(int cn=0;cn<4;cn++){ oacc[qt][cn].x=0.f; oacc[qt][cn].y=0.f; oacc[qt][cn].z=0.f; oacc[qt][cn].w=0.f; }

  auto tilestep=[&](const u32* Kb,const u32* Vb){
    f32x4 sv[2][4];
    #pragma unroll
    for(int nt=0;nt<4;nt++){
      const u32* kb=Kb+(nt*16+l15)*34+quad*4;
      u32x4 k0=ldfrag(kb), k1=ldfrag(kb+16);
      #pragma unroll
      for(int qt=0;qt<2;qt++){
        f32x4 a; a.x=0.f; a.y=0.f; a.z=0.f; a.w=0.f;
        a=mfma16(k0,qf[qt][0],a);
        sv[qt][nt]=mfma16(k1,qf[qt][1],a);
      }
    }
    s16x4 pfr[2][4];
    #pragma unroll
    for(int qt=0;qt<2;qt++)
      #pragma unroll
      for(int nt=0;nt<4;nt++){
        float p0=fexp2(sv[qt][nt].x),p1=fexp2(sv[qt][nt].y),p2=fexp2(sv[qt][nt].z),p3=fexp2(sv[qt][nt].w);
        lrun[qt]+=(p0+p1)+(p2+p3);
        u32x2 pp;
        pp.x=(__builtin_bit_cast(u32,p0)>>16)|(__builtin_bit_cast(u32,p1)&0xffff0000u);
        pp.y=(__builtin_bit_cast(u32,p2)>>16)|(__builtin_bit_cast(u32,p3)&0xffff0000u);
        pfr[qt][nt]=__builtin_bit_cast(s16x4,pp);
      }
    #pragma unroll
    for(int cn=0;cn<4;cn++){
      const u32* vb=Vb+(cn*16+l15)*34+quad*2;
      f32x4 a0=oacc[0][cn], a1=oacc[1][cn];
      #pragma unroll
      for(int nt=0;nt<4;nt++){
        s16x4 vf=ld8(vb+nt*8);
        a0=mfma1k(pfr[0][nt],vf,a0);
        a1=mfma1k(pfr[1][nt],vf,a1);
      }
      oacc[0][cn]=a0; oacc[1][cn]=a1;
    }
  };

  loadKV(0); writeKV(KS[half][0],VS[half][0]);
  __syncthreads();
  for(int t0=0;t0<2048;t0+=128){
    loadKV(t0+64);
    tilestep(KS[half][0],VS[half][0]);
    writeKV(KS[half][1],VS[half][1]);
    __syncthreads();
    const bool more=(t0+128)<2048;
    if(more) loadKV(t0+128);
    tilestep(KS[half][1],VS[half][1]);
    if(more){ writeKV(KS[half][0],VS[half][0]); __syncthreads(); }
  }
  // merge halves through LDS (reuse KS; all K reads done)
  __syncthreads();
  float* cb=(float*)KS;
  const int cbi=(wq*64+lane)*34;
  if(half==1){
    #pragma unroll
    for(int qt=0;qt<2;qt++)
      #pragma unroll
      for(int cn=0;cn<4;cn++)
        #pragma unroll
        for(int r4=0;r4<4;r4++) cb[cbi+qt*16+cn*4+r4]=oacc[qt][cn][r4];
    cb[cbi+32]=lrun[0]; cb[cbi+33]=lrun[1];
  }
  __syncthreads();
  if(half==0){
    #pragma unroll
    for(int qt=0;qt<2;qt++){
      #pragma unroll
      for(int cn=0;cn<4;cn++)
        #pragma unroll
        for(int r4=0;r4<4;r4++) oacc[qt][cn][r4]+=cb[cbi+qt*16+cn*4+r4];
      float l=lrun[qt]+cb[cbi+32+qt];
      l+=__shfl_xor(l,16,64);
      l+=__shfl_xor(l,32,64);
      #pragma unroll
      for(int r4=0;r4<4;r4++){
        float inv=1.f/__shfl(l,quad*4+r4,64);
        #pragma unroll
        for(int cn=0;cn<4;cn++)
          Oh[((size_t)(h*4096+q0+qt*64+wq*16+quad*4+r4))*64 + cn*16 + l15]=f2bf(oacc[qt][cn][r4]*inv);
      }
    }
  }
}

// ------------------------------- launcher -------------------------------------
extern "C" void kernel_launch(void* const* d_in, const int* in_sizes, int n_in,
                              void* d_out, int out_size, void* d_ws, size_t ws_size,
                              hipStream_t stream){
  (void)in_sizes; (void)n_in; (void)out_size; (void)ws_size;
  const float* x  =(const float*)d_in[0];
  const float* ctx=(const float*)d_in[1];
  const float* nw =(const float*)d_in[2];
  const float* nb =(const float*)d_in[3];
  const float* ncw=(const float*)d_in[4];
  const float* ncb=(const float*)d_in[5];
  const float* qw =(const float*)d_in[6];
  const float* qb =(const float*)d_in[7];
  const float* kvw=(const float*)d_in[8];
  const float* kvb=(const float*)d_in[9];
  const float* pw =(const float*)d_in[10];
  const float* pb =(const float*)d_in[11];
  float* out=(float*)d_out;
  char* ws=(char*)d_ws;
  float* stats=(float*)ws;                    // 1 KB
  u16* Wall=(u16*)(ws+1024);                  // 2 MB: [pwb][qwb][kvwb]
  u16* pwb  = Wall;
  u16* qwb  = Wall+262144;
  u16* kvw1b= Wall+524288;
  u16* kvw2b= Wall+786432;
  u16* cnT=(u16*)(ws+2098176);                // [4096][512] bf16, 4 MB
  u16* xnT=(u16*)(ws+6292480);                // 4 MB
  u16* Qh =(u16*)(ws+10486784);               // [8][4096][64]
  u16* Kh =(u16*)(ws+14681088);               // ends 18875392 (~18.0 MB)
  u16* Vp =(u16*)(ws+6292480);                // overlays xnT (dead after Q/K GEMM)
  u16* Oh =(u16*)(ws+2098176);                // overlays cnT (dead after V GEMM)

  k_stats<<<dim3(128),dim3(256),0,stream>>>(x,ctx,stats);
  k_norm<<<dim3(288),dim3(256),0,stream>>>(x,ctx,qw,kvw,pw,nw,nb,ncw,ncb,stats,xnT,cnT,Wall);
  // Q (z=0) and K (z=1) in one dispatch
  k_gemm<0,0,1><<<dim3(512),dim3(256),0,stream>>>(xnT,cnT,qwb,kvw1b,qb,kvb,nullptr,Qh,Kh,0.125f*LOG2E,1.f);
  // V[co][s] = Wv · cn
  k_gemm<1,0,0><<<dim3(256),dim3(256),0,stream>>>(kvw2b,nullptr,cnT,nullptr,kvb+512,nullptr,nullptr,Vp,nullptr,1.f,1.f);
  k_attn<<<dim3(32,8),dim3(512),0,stream>>>(Qh,Kh,Vp,Oh);
  // proj + residual (fp32 out)
  k_gemm<2,1,0><<<dim3(256),dim3(256),0,stream>>>(pwb,nullptr,Oh,nullptr,pb,nullptr,x,out,nullptr,1.f,1.f);
}

// Round 11
// 175.324 us; speedup vs baseline: 1.0703x; 1.0337x over previous
//
#include <hip/hip_runtime.h>

typedef unsigned short u16;
typedef unsigned int u32;
typedef float f32x4 __attribute__((ext_vector_type(4)));
typedef __bf16 bf16x8 __attribute__((ext_vector_type(8)));
typedef u32 u32x4 __attribute__((ext_vector_type(4)));
typedef u32 u32x2 __attribute__((ext_vector_type(2)));
typedef short s16x4 __attribute__((ext_vector_type(4)));

#define LOG2E 1.44269504088896340736f

static __device__ __forceinline__ u16 f2bf(float f){ u32 u=__builtin_bit_cast(u32,f); u32 r=u+0x7fffu+((u>>16)&1u); return (u16)(r>>16); }
static __device__ __forceinline__ u32 pk2(float a,float b){ return (u32)f2bf(a)|((u32)f2bf(b)<<16); }
static __device__ __forceinline__ float fexp2(float x){
#if __has_builtin(__builtin_amdgcn_exp2f)
  return __builtin_amdgcn_exp2f(x);
#else
  float r; asm volatile("v_exp_f32 %0, %1" : "=v"(r) : "v"(x)); return r;
#endif
}
static __device__ __forceinline__ f32x4 mfma16(u32x4 a,u32x4 b,f32x4 c){
  return __builtin_amdgcn_mfma_f32_16x16x32_bf16(__builtin_bit_cast(bf16x8,a),__builtin_bit_cast(bf16x8,b),c,0,0,0);
}
#if __has_builtin(__builtin_amdgcn_mfma_f32_16x16x16bf16_1k)
static __device__ __forceinline__ f32x4 mfma1k(s16x4 a,s16x4 b,f32x4 c){
  return __builtin_amdgcn_mfma_f32_16x16x16bf16_1k(a,b,c,0,0,0);
}
#else
static __device__ __forceinline__ f32x4 mfma1k(s16x4 a,s16x4 b,f32x4 c){
  f32x4 d; asm("v_mfma_f32_16x16x16_bf16 %0, %1, %2, %3":"=v"(d):"v"(a),"v"(b),"v"(c)); return d;
}
#endif
static __device__ __forceinline__ u32x4 ldfrag(const u32* p){
  uint2 a=*(const uint2*)p; uint2 b=*(const uint2*)(p+2);
  u32x4 r; r.x=a.x; r.y=a.y; r.z=b.x; r.w=b.y; return r;
}
static __device__ __forceinline__ u32x4 ld16(const u32* p){ return *(const u32x4*)p; }
static __device__ __forceinline__ s16x4 ld8(const u32* p){
  return __builtin_bit_cast(s16x4, *(const u32x2*)p);
}
static __device__ __forceinline__ void stlds(u32* d, uint4 v){
  *(uint2*)d = make_uint2(v.x,v.y); *(uint2*)(d+2) = make_uint2(v.z,v.w);
}
static __device__ __forceinline__ uint4 pack8(float4 a,float4 b){
  uint4 o; o.x=pk2(a.x,a.y); o.y=pk2(a.z,a.w); o.z=pk2(b.x,b.y); o.w=pk2(b.z,b.w); return o;
}

// ------------- group-norm stats: per-(group,slice) partial sums ---------------
__global__ __launch_bounds__(256) void k_stats(const float* __restrict__ x, const float* __restrict__ c,
                                               float* __restrict__ stats){
  const int g=blockIdx.x>>3;
  const float* src=(g<8?x:c)+(size_t)(g&7)*262144+(size_t)(blockIdx.x&7)*32768;
  const float4* p=(const float4*)src;
  const int t=threadIdx.x;
  float s1=0.f,s2=0.f;
  for(int i=0;i<32;i++){
    float4 v=p[t+i*256];
    s1+=v.x+v.y+v.z+v.w;
    s2+=v.x*v.x+v.y*v.y+v.z*v.z+v.w*v.w;
  }
  #pragma unroll
  for(int m=1;m<64;m<<=1){ s1+=__shfl_xor(s1,m,64); s2+=__shfl_xor(s2,m,64); }
  __shared__ float r1[4],r2[4];
  const int lane=t&63,w=t>>6;
  if(lane==0){ r1[w]=s1; r2[w]=s2; }
  __syncthreads();
  if(t==0){
    stats[blockIdx.x*2  ]=r1[0]+r1[1]+r1[2]+r1[3];
    stats[blockIdx.x*2+1]=r2[0]+r2[1]+r2[2]+r2[3];
  }
}

// -------- k_norm: (a) normalize+transpose x/ctx -> bf16 [s][c]; (b) weights->bf16
__global__ __launch_bounds__(256) void k_norm(const float* __restrict__ x,const float* __restrict__ ctx,
    const float* __restrict__ qw,const float* __restrict__ kvw,const float* __restrict__ pw,
    const float* __restrict__ nw,const float* __restrict__ nb,
    const float* __restrict__ ncw,const float* __restrict__ ncb,
    const float* __restrict__ stats,
    u16* __restrict__ xnT,u16* __restrict__ cnT,u16* __restrict__ Wall){
  const int bid=blockIdx.x, t=threadIdx.x;
  if(bid>=256){
    const int wb=bid-256;
    const float* src = wb<8 ? pw+(size_t)wb*32768 : (wb<16 ? qw+(size_t)(wb-8)*32768 : kvw+(size_t)(wb-16)*32768);
    u16* dst = Wall + (size_t)wb*32768;
    #pragma unroll
    for(int it=0;it<16;it++){
      int off = it*2048 + t*8;
      float4 a=*(const float4*)(src+off), b=*(const float4*)(src+off+4);
      *(uint4*)(dst+off) = pack8(a,b);
    }
    return;
  }
  const int op=bid>>7, r=bid&127;
  const int c0=(r>>4)*64, s0=(r&15)*256;
  const float* src = op? ctx : x;
  u16* dst = op? cnT : xnT;
  const float* anw = op? ncw : nw;
  const float* anb = op? ncb : nb;
  __shared__ float al[64], bt[64];
  __shared__ u32 T[256*37];
  if(t<64){
    int c=c0+t, g=(op?8:0)+(c>>6);
    float s1=0.f,s2=0.f;
    #pragma unroll
    for(int s=0;s<8;s++){ s1+=stats[(g*8+s)*2]; s2+=stats[(g*8+s)*2+1]; }
    float mean=s1*(1.f/262144.f);
    float var =s2*(1.f/262144.f)-mean*mean;
    float a=anw[c]*rsqrtf(var+1e-5f);
    al[t]=a; bt[t]=anb[c]-mean*a;
  }
  __syncthreads();
  const int pr=t>>3, sj=(t&7)*8;
  const float a0=al[2*pr], b0=bt[2*pr], a1=al[2*pr+1], b1=bt[2*pr+1];
  #pragma unroll
  for(int it=0;it<4;it++){
    int ls=it*64+sj;
    const float* p0=src+(size_t)(c0+2*pr)*4096+s0+ls;
    const float* p1=src+(size_t)(c0+2*pr+1)*4096+s0+ls;
    float4 va=*(const float4*)p0, vb=*(const float4*)(p0+4);
    float4 vc=*(const float4*)p1, vd=*(const float4*)(p1+4);
    float f0[8]={va.x,va.y,va.z,va.w,vb.x,vb.y,vb.z,vb.w};
    float f1[8]={vc.x,vc.y,vc.z,vc.w,vd.x,vd.y,vd.z,vd.w};
    #pragma unroll
    for(int j=0;j<8;j++)
      T[(ls+j)*37+pr]=pk2(a0*f0[j]+b0, a1*f1[j]+b1);
  }
  __syncthreads();
  #pragma unroll
  for(int ps=0;ps<8;ps++){
    int row = ps*32 + (t>>3);
    const u32* rp=&T[row*37+(t&7)*4];
    u32 v0=rp[0],v1=rp[1],v2=rp[2],v3=rp[3];
    *(uint4*)(dst + (size_t)(s0+row)*512 + c0 + (t&7)*8) = make_uint4(v0,v1,v2,v3);
  }
}

// --------- unified bf16 BT GEMM: C[m][n]=sum_k A[m][k]B[n][k], K=512 ----------
// BM=64, BN=128, BK=64 (8 phases, half the barrier drains of BK=32), 256 thr,
// wave tile 32x64. LDS rows: 64 halves @ stride-34 u32 — the attn-proven
// 0-conflict pattern (frag reads at ks*16+quad*4). Dbuf, unrolled x2.
// EPI 0: head-layout store (m=s, n=co), bias[n], *scale (Q/K; ZS selects set)
// EPI 1: bf16 out[m*4096+n]+bias[m]  (V)
template<int EPI,int ZS>
__global__ __launch_bounds__(256) void k_gemm(const u16* __restrict__ A0,const u16* __restrict__ A1,
    const u16* __restrict__ B0,const u16* __restrict__ B1,
    const float* __restrict__ bias0,const float* __restrict__ bias1,
    void* __restrict__ out0,void* __restrict__ out1,
    float scale0,float scale1){
  __shared__ __align__(16) u32 As[2][64*34];
  __shared__ __align__(16) u32 Bs[2][128*34];
  const int t=threadIdx.x, lane=t&63, w=t>>6;
  const int wm=w&1, wn=w>>1, quad=lane>>4, l15=lane&15;
  const int bid=blockIdx.x;
  const int z = ZS ? (bid>>8) : 0;
  const int r = ZS ? (bid&255) : bid;
  const u16* A = z? A1:A0;
  const u16* B = z? B1:B0;
  const float* bias = z? bias1:bias0;
  void* outv = z? out1:out0;
  const float scale = z? scale1:scale0;
  int m0,n0;
  if(EPI==0){ m0=(r>>2)*64; n0=(r&3)*128; }
  else      { m0=(r>>5)*64; n0=(r&31)*128; }
  const int arow=t>>2, ak=(t&3)*16;   // A: 64 rows x 64 halves, 2 uint4/thr
  const int brow=t>>1, bk=(t&1)*32;   // B: 128 rows x 64 halves, 4 uint4/thr
  uint4 a0,a1,b0,b1,b2,b3;
  auto loadAB=[&](int kk){
    const u16* ap=A+(size_t)(m0+arow)*512+kk+ak;
    a0=*(const uint4*)ap; a1=*(const uint4*)(ap+8);
    const u16* bp=B+(size_t)(n0+brow)*512+kk+bk;
    b0=*(const uint4*)bp; b1=*(const uint4*)(bp+8);
    b2=*(const uint4*)(bp+16); b3=*(const uint4*)(bp+24);
  };
  auto writeAB=[&](int bsel){
    u32* aw=&As[bsel][arow*34+(ak>>1)];
    stlds(aw,a0); stlds(aw+4,a1);
    u32* bw=&Bs[bsel][brow*34+(bk>>1)];
    stlds(bw,b0); stlds(bw+4,b1); stlds(bw+8,b2); stlds(bw+12,b3);
  };
  f32x4 acc[2][4];
  #pragma unroll
  for(int i=0;i<2;i++)
    #pragma unroll
    for(int j=0;j<4;j++){ acc[i][j].x=0.f; acc[i][j].y=0.f; acc[i][j].z=0.f; acc[i][j].w=0.f; }
  auto compute=[&](int bsel){
    #pragma unroll
    for(int ks=0;ks<2;ks++){
      const u32* Ab=&As[bsel][(wm*32+l15)*34+ks*16+quad*4];
      const u32* Bb=&Bs[bsel][(wn*64+l15)*34+ks*16+quad*4];
      u32x4 af[2], bf[4];
      #pragma unroll
      for(int mt=0;mt<2;mt++) af[mt]=ldfrag(Ab+mt*544);
      #pragma unroll
      for(int nt=0;nt<4;nt++) bf[nt]=ldfrag(Bb+nt*544);
      #pragma unroll
      for(int mt=0;mt<2;mt++)
        #pragma unroll
        for(int nt=0;nt<4;nt++) acc[mt][nt]=mfma16(af[mt],bf[nt],acc[mt][nt]);
    }
  };
  loadAB(0); writeAB(0);
  __syncthreads();
  for(int kk=0;kk<512;kk+=128){
    loadAB(kk+64);
    compute(0);
    writeAB(1);
    __syncthreads();
    const bool n2=(kk+128)<512;
    if(n2) loadAB(kk+128);
    compute(1);
    if(n2){ writeAB(0); __syncthreads(); }
  }
  #pragma unroll
  for(int mt=0;mt<2;mt++)
    #pragma unroll
    for(int nt=0;nt<4;nt++){
      const int n = n0 + wn*64 + nt*16 + l15;
      if(EPI==0){
        u16* out=(u16*)outv;
        const float bn=bias[n];
        const size_t base=((size_t)((n>>6)*4096))*64+(size_t)(n&63);
        #pragma unroll
        for(int r4=0;r4<4;r4++){
          int m=m0+wm*32+mt*16+quad*4+r4;
          out[base+(size_t)m*64]=f2bf((acc[mt][nt][r4]+bn)*scale);
        }
      }else{
        u16* out=(u16*)outv;
        #pragma unroll
        for(int r4=0;r4<4;r4++){
          int m=m0+wm*32+mt*16+quad*4+r4;
          out[(size_t)m*4096+n]=f2bf(acc[mt][nt][r4]+bias[m]);
        }
      }
    }
}

// ---- proj GEMM: 64x64 tiles (grid 512 = 2 blocks/CU), BK=64, B from Oh ------
__global__ __launch_bounds__(256) void k_proj(const u16* __restrict__ pwb,const u16* __restrict__ Oh,
    const float* __restrict__ pb,const float* __restrict__ x,float* __restrict__ out){
  __shared__ __align__(16) u32 As[2][64*34];
  __shared__ __align__(16) u32 Bs[2][64*34];
  const int t=threadIdx.x, lane=t&63, w=t>>6;
  const int wm=w&1, wn=w>>1, quad=lane>>4, l15=lane&15;
  const int m0=blockIdx.y*64, n0=blockIdx.x*64;
  const int arow=t>>2, ak=(t&3)*16;
  uint4 a0,a1,b0,b1;
  auto loadAB=[&](int kk){
    const u16* ap=pwb+(size_t)(m0+arow)*512+kk+ak;
    a0=*(const uint4*)ap; a1=*(const uint4*)(ap+8);
    const u16* bp=Oh+((size_t)((kk>>6)*4096+n0+arow))*64+ak;
    b0=*(const uint4*)bp; b1=*(const uint4*)(bp+8);
  };
  auto writeAB=[&](int bsel){
    u32* aw=&As[bsel][arow*34+(ak>>1)];
    stlds(aw,a0); stlds(aw+4,a1);
    u32* bw=&Bs[bsel][arow*34+(ak>>1)];
    stlds(bw,b0); stlds(bw+4,b1);
  };
  f32x4 acc[2][2];
  #pragma unroll
  for(int i=0;i<2;i++)
    #pragma unroll
    for(int j=0;j<2;j++){ acc[i][j].x=0.f; acc[i][j].y=0.f; acc[i][j].z=0.f; acc[i][j].w=0.f; }
  auto compute=[&](int bsel){
    #pragma unroll
    for(int ks=0;ks<2;ks++){
      const u32* Ab=&As[bsel][(wm*32+l15)*34+ks*16+quad*4];
      const u32* Bb=&Bs[bsel][(wn*32+l15)*34+ks*16+quad*4];
      u32x4 af[2], bf[2];
      #pragma unroll
      for(int mt=0;mt<2;mt++) af[mt]=ldfrag(Ab+mt*544);
      #pragma unroll
      for(int nt=0;nt<2;nt++) bf[nt]=ldfrag(Bb+nt*544);
      #pragma unroll
      for(int mt=0;mt<2;mt++)
        #pragma unroll
        for(int nt=0;nt<2;nt++) acc[mt][nt]=mfma16(af[mt],bf[nt],acc[mt][nt]);
    }
  };
  loadAB(0); writeAB(0);
  __syncthreads();
  for(int kk=0;kk<512;kk+=128){
    loadAB(kk+64);
    compute(0);
    writeAB(1);
    __syncthreads();
    const bool n2=(kk+128)<512;
    if(n2) loadAB(kk+128);
    compute(1);
    if(n2){ writeAB(0); __syncthreads(); }
  }
  #pragma unroll
  for(int mt=0;mt<2;mt++)
    #pragma unroll
    for(int nt=0;nt<2;nt++){
      const int n = n0 + wn*32 + nt*16 + l15;
      #pragma unroll
      for(int r4=0;r4<4;r4++){
        int m=m0+wm*32+mt*16+quad*4+r4;
        out[(size_t)m*4096+n]=acc[mt][nt][r4]+pb[m]+x[(size_t)m*4096+n];
      }
    }
}

// -------- flash attention: 128q blocks, 2 q-frags/wave, split-K halves --------
// (R10-proven: stride-34, 0 conflicts, 59 us) — unchanged this round.
__global__ __launch_bounds__(512) void k_attn(const u16* __restrict__ Qh,const u16* __restrict__ Kh,
                                              const u16* __restrict__ Vp,u16* __restrict__ Oh){
  __shared__ __align__(16) u32 KS[2][2][64*34];   // [half][buf][key][c]
  __shared__ __align__(16) u32 VS[2][2][64*34];   // [half][buf][c][key]
  const int t=threadIdx.x, lane=t&63, w=t>>6, quad=lane>>4, l15=lane&15;
  const int half=w>>2, wq=w&3;
  const int h=blockIdx.y, q0=blockIdx.x*128;
  const int tt=t&255, srow=tt>>2, sc=(tt&3)*16;
  const u16* Kg = Kh + ((size_t)(h*4096 + half*2048 + srow))*64 + sc;
  const u16* Vg = Vp + (size_t)(h*64+srow)*4096 + half*2048 + sc;
  u32x4 qf[2][2];
  #pragma unroll
  for(int qt=0;qt<2;qt++){
    const u32* Qg=(const u32*)(Qh + ((size_t)(h*4096+q0+qt*64+wq*16+l15))*64);
    qf[qt][0]=ld16(Qg+quad*4);
    qf[qt][1]=ld16(Qg+16+quad*4);
  }
  uint4 pk0,pk1,pv0,pv1;
  auto loadKV=[&](int t0l){
    const u16* kp=Kg+(size_t)t0l*64;
    pk0=*(const uint4*)kp; pk1=*(const uint4*)(kp+8);
    const u16* vp=Vg+t0l;
    pv0=*(const uint4*)vp; pv1=*(const uint4*)(vp+8);
  };
  auto writeKV=[&](u32* Kb,u32* Vb){
    u32* kw=Kb+srow*34+(sc>>1);
    stlds(kw,pk0); stlds(kw+4,pk1);
    u32* vw=Vb+srow*34+(sc>>1);
    stlds(vw,pv0); stlds(vw+4,pv1);
  };
  float lrun[2]={0.f,0.f};
  f32x4 oacc[2][4];
  #pragma unroll
  for(int qt=0;qt<2;qt++)
    #pragma unroll
    for(int cn=0;cn<4;cn++){ oacc[qt][cn].x=0.f; oacc[qt][cn].y=0.f; oacc[qt][cn].z=0.f; oacc[qt][cn].w=0.f; }

  auto tilestep=[&](const u32* Kb,const u32* Vb){
    f32x4 sv[2][4];
    #pragma unroll
    for(int nt=0;nt<4;nt++){
      const u32* kb=Kb+(nt*16+l15)*34+quad*4;
      u32x4 k0=ldfrag(kb), k1=ldfrag(kb+16);
      #pragma unroll
      for(int qt=0;qt<2;qt++){
        f32x4 a; a.x=0.f; a.y=0.f; a.z=0.f; a.w=0.f;
        a=mfma16(k0,qf[qt][0],a);
        sv[qt][nt]=mfma16(k1,qf[qt][1],a);
      }
    }
    s16x4 pfr[2][4];
    #pragma unroll
    for(int qt=0;qt<2;qt++)
      #pragma unroll
      for(int nt=0;nt<4;nt++){
        float p0=fexp2(sv[qt][nt].x),p1=fexp2(sv[qt][nt].y),p2=fexp2(sv[qt][nt].z),p3=fexp2(sv[qt][nt].w);
        lrun[qt]+=(p0+p1)+(p2+p3);
        u32x2 pp;
        pp.x=(__builtin_bit_cast(u32,p0)>>16)|(__builtin_bit_cast(u32,p1)&0xffff0000u);
        pp.y=(__builtin_bit_cast(u32,p2)>>16)|(__builtin_bit_cast(u32,p3)&0xffff0000u);
        pfr[qt][nt]=__builtin_bit_cast(s16x4,pp);
      }
    #pragma unroll
    for(int cn=0;cn<4;cn++){
      const u32* vb=Vb+(cn*16+l15)*34+quad*2;
      f32x4 a0=oacc[0][cn], a1=oacc[1][cn];
      #pragma unroll
      for(int nt=0;nt<4;nt++){
        s16x4 vf=ld8(vb+nt*8);
        a0=mfma1k(pfr[0][nt],vf,a0);
        a1=mfma1k(pfr[1][nt],vf,a1);
      }
      oacc[0][cn]=a0; oacc[1][cn]=a1;
    }
  };

  loadKV(0); writeKV(KS[half][0],VS[half][0]);
  __syncthreads();
  for(int t0=0;t0<2048;t0+=128){
    loadKV(t0+64);
    tilestep(KS[half][0],VS[half][0]);
    writeKV(KS[half][1],VS[half][1]);
    __syncthreads();
    const bool more=(t0+128)<2048;
    if(more) loadKV(t0+128);
    tilestep(KS[half][1],VS[half][1]);
    if(more){ writeKV(KS[half][0],VS[half][0]); __syncthreads(); }
  }
  __syncthreads();
  float* cb=(float*)KS;
  const int cbi=(wq*64+lane)*34;
  if(half==1){
    #pragma unroll
    for(int qt=0;qt<2;qt++)
      #pragma unroll
      for(int cn=0;cn<4;cn++)
        #pragma unroll
        for(int r4=0;r4<4;r4++) cb[cbi+qt*16+cn*4+r4]=oacc[qt][cn][r4];
    cb[cbi+32]=lrun[0]; cb[cbi+33]=lrun[1];
  }
  __syncthreads();
  if(half==0){
    #pragma unroll
    for(int qt=0;qt<2;qt++){
      #pragma unroll
      for(int cn=0;cn<4;cn++)
        #pragma unroll
        for(int r4=0;r4<4;r4++) oacc[qt][cn][r4]+=cb[cbi+qt*16+cn*4+r4];
      float l=lrun[qt]+cb[cbi+32+qt];
      l+=__shfl_xor(l,16,64);
      l+=__shfl_xor(l,32,64);
      #pragma unroll
      for(int r4=0;r4<4;r4++){
        float inv=1.f/__shfl(l,quad*4+r4,64);
        #pragma unroll
        for(int cn=0;cn<4;cn++)
          Oh[((size_t)(h*4096+q0+qt*64+wq*16+quad*4+r4))*64 + cn*16 + l15]=f2bf(oacc[qt][cn][r4]*inv);
      }
    }
  }
}

// ------------------------------- launcher -------------------------------------
extern "C" void kernel_launch(void* const* d_in, const int* in_sizes, int n_in,
                              void* d_out, int out_size, void* d_ws, size_t ws_size,
                              hipStream_t stream){
  (void)in_sizes; (void)n_in; (void)out_size; (void)ws_size;
  const float* x  =(const float*)d_in[0];
  const float* ctx=(const float*)d_in[1];
  const float* nw =(const float*)d_in[2];
  const float* nb =(const float*)d_in[3];
  const float* ncw=(const float*)d_in[4];
  const float* ncb=(const float*)d_in[5];
  const float* qw =(const float*)d_in[6];
  const float* qb =(const float*)d_in[7];
  const float* kvw=(const float*)d_in[8];
  const float* kvb=(const float*)d_in[9];
  const float* pw =(const float*)d_in[10];
  const float* pb =(const float*)d_in[11];
  float* out=(float*)d_out;
  char* ws=(char*)d_ws;
  float* stats=(float*)ws;                    // 1 KB
  u16* Wall=(u16*)(ws+1024);                  // 2 MB: [pwb][qwb][kvwb]
  u16* pwb  = Wall;
  u16* qwb  = Wall+262144;
  u16* kvw1b= Wall+524288;
  u16* kvw2b= Wall+786432;
  u16* cnT=(u16*)(ws+2098176);                // [4096][512] bf16, 4 MB
  u16* xnT=(u16*)(ws+6292480);                // 4 MB
  u16* Qh =(u16*)(ws+10486784);               // [8][4096][64]
  u16* Kh =(u16*)(ws+14681088);               // ends 18875392 (~18.0 MB)
  u16* Vp =(u16*)(ws+6292480);                // overlays xnT (dead after Q/K GEMM)
  u16* Oh =(u16*)(ws+2098176);                // overlays cnT (dead after V GEMM)

  k_stats<<<dim3(128),dim3(256),0,stream>>>(x,ctx,stats);
  k_norm<<<dim3(288),dim3(256),0,stream>>>(x,ctx,qw,kvw,pw,nw,nb,ncw,ncb,stats,xnT,cnT,Wall);
  // Q (z=0) and K (z=1) in one dispatch
  k_gemm<0,1><<<dim3(512),dim3(256),0,stream>>>(xnT,cnT,qwb,kvw1b,qb,kvb,Qh,Kh,0.125f*LOG2E,1.f);
  // V[co][s] = Wv · cn
  k_gemm<1,0><<<dim3(256),dim3(256),0,stream>>>(kvw2b,nullptr,cnT,nullptr,kvb+512,nullptr,Vp,nullptr,1.f,1.f);
  k_attn<<<dim3(32,8),dim3(512),0,stream>>>(Qh,Kh,Vp,Oh);
  // proj + residual (fp32 out), 64x64 tiles -> 512 blocks
  k_proj<<<dim3(64,8),dim3(256),0,stream>>>(pwb,Oh,pb,x,out);
}